// Round 9
// baseline (11984.578 us; speedup 1.0000x reference)
//
#include <hip/hip_runtime.h>
#include <hip/hip_fp16.h>

typedef _Float16 f16x8 __attribute__((ext_vector_type(8)));
typedef float f32x4 __attribute__((ext_vector_type(4)));
typedef unsigned short u16;
typedef unsigned int u32;

#define T_STEPS 512
#define BATCH   512
#define DTF     0.01f

// workspace layout (bytes)
#define CTR_OFF 0
#define CTR_SZ  1048576                     // slot counters + per-(g,t) barrier counters
#define WB_OFF  (CTR_OFF + CTR_SZ)
#define WB_SZ   (32*2*76800)                // 4,915,200  packed W_h+W_p f16 frags, 32 slices
#define WRB_OFF (WB_OFF + WB_SZ)
#define WRB_SZ  (4*24*64*8*2)               // 98,304     W_r f16 B-frag layout
#define ST_OFF  (WRB_OFF + WRB_SZ)
#define ST_SZ   (2*8*4*48*64*8*2)           // 3,145,728  state in A-FRAGMENT layout
                                            //   [buf][g][w][kt2(48)][lane(64)][8] f16
#define WS_NEED (ST_OFF + ST_SZ)

#define MFMA16(a,b,c) __builtin_amdgcn_mfma_f32_16x16x32_f16((a),(b),(c),0,0,0)

// Intra-XCD acquire: L2 is the coherence point (peers on this XCD by
// construction), L1 is write-through => only L1 can be stale. L1-only inv,
// one wave per CU before the barrier. [Verified rounds 3-8.]
#define ACQUIRE_L1() asm volatile("s_waitcnt vmcnt(0)\n\tbuffer_inv sc0" ::: "memory")

__device__ __forceinline__ u16 f2h(float f){ _Float16 h = (_Float16)f; return *reinterpret_cast<u16*>(&h); }

__device__ __forceinline__ float ftanh(float x){
  float a = fminf(fmaxf(x, -12.f), 12.f);
  float e = __expf(2.f * a);
  return 1.f - 2.f * __builtin_amdgcn_rcpf(e + 1.f);
}

// Packed per-slice weight image (u16 units), slice s owns cols [s*24, s*24+24)
// of BOTH matrices (identity K order: k<64 -> x, 64..831 -> hz, 832.. -> hy):
//   base = s*76800 ; mat m in {0=W_h,1=W_p}: mbase = base + m*38400
//   nt0 full frags : mbase + kt*512 + l*8          (l=0..63)  col = s*24 + (l&15),   k = kt*32+(l>>4)*8
//   nt1 half frags : mbase + 25600 + kt*256 + j*8  (j=0..31)  col = s*24+16 + (j&7), k = kt*32+(j>>3)*8
// Wrb[nt(4)][kt(24)][lane(64)][8] for the final projection.
__global__ __launch_bounds__(64) void prep_weights(const float* __restrict__ Wh,
                                                   const float* __restrict__ Wp,
                                                   const float* __restrict__ Wr,
                                                   u16* __restrict__ Wb, u16* __restrict__ Wrb){
  int b = blockIdx.x, l = threadIdx.x;
  if (b < 3200){
    int s = b / 100, rem = b % 100;
    int m = rem / 50, kt = rem % 50;
    const float* W = m ? Wp : Wh;
    size_t mbase = (size_t)s*76800 + (size_t)m*38400;
    {
      int col = s*24 + (l & 15), k = kt*32 + (l >> 4)*8;
      const float* src = W + (size_t)col*1600 + k;
      f16x8 o;
#pragma unroll
      for (int e = 0; e < 8; ++e) o[e] = (_Float16)src[e];
      *reinterpret_cast<f16x8*>(Wb + mbase + (size_t)kt*512 + (size_t)l*8) = o;
    }
    if (l < 32){
      int col = s*24 + 16 + (l & 7), k = kt*32 + (l >> 3)*8;
      const float* src = W + (size_t)col*1600 + k;
      f16x8 o;
#pragma unroll
      for (int e = 0; e < 8; ++e) o[e] = (_Float16)src[e];
      *reinterpret_cast<f16x8*>(Wb + mbase + 25600 + (size_t)kt*256 + (size_t)l*8) = o;
    }
  } else {
    int b2 = b - 3200;                      // 0..95
    int nt = b2 / 24, kt = b2 % 24;
    int c = nt*16 + (l & 15), k = kt*32 + (l >> 4)*8;
    const float* src = Wr + (size_t)c*768 + k;
    f16x8 o;
#pragma unroll
    for (int e = 0; e < 8; ++e) o[e] = (_Float16)src[e];
    *reinterpret_cast<f16x8*>(Wrb + ((size_t)b2*64 + l)*8) = o;
  }
}

// grid = 256 x 256. Group = PHYSICAL XCD (HW_REG_XCC_ID), slot via atomicAdd:
// 32 blocks/XCD (1 block/CU by LDS). Slot s owns out-cols [s*24,+24) of BOTH
// W_h/W_p. STATE IS STORED IN A-FRAGMENT LAYOUT: consumer wave w's K-tile
// reads are single fully-contiguous 1KB dwordx4 loads, issued 24 deep (high
// MLP) — this attacks the scattered-read/low-MLP stall that six sync variants
// could not move. Sync = r6's single per-(g,t) counter (verified simplest).
__global__ __launch_bounds__(256, 1) void rnn_main(
    const float* __restrict__ x, const float* __restrict__ bh_g, const float* __restrict__ bp_g,
    const float* __restrict__ br_g, const u16* __restrict__ Wb, const u16* __restrict__ Wrb,
    u16* __restrict__ st, u32* __restrict__ ctr, float* __restrict__ out)
{
  extern __shared__ u16 smem[];             // packed weight slice, 153,600 B
  __shared__ int s_dead, s_slot, s_xcd;

  const int tid = threadIdx.x;
  if (tid == 0){
    s_dead = 0;
    u32 xcd;
    asm volatile("s_getreg_b32 %0, hwreg(HW_REG_XCC_ID)" : "=s"(xcd));
    xcd &= 7u;
    s_xcd  = (int)xcd;
    s_slot = (int)atomicAdd(ctr + xcd, 1u); // device-scope, ctr pre-zeroed
  }
  __syncthreads();
  const int g = s_xcd;
  const int s = s_slot;
  if (s >= 32) return;

  const int c0   = s * 24;
  const int l    = tid & 63;
  const int w    = tid >> 6;
  const int colL = l & 15;
  const int kq   = l >> 4;
  const int j8   = kq*8 + (l & 7);          // nt1 half-frag index
  const int rowA = w*16 + colL;             // A-frag row for x loads
  const bool v1  = (colL < 8);              // nt1 validity

  // per-(g,t) barrier counters: ctr[2048 + g*16384 + t*32], 128B stride  [r6]
  u32* FL = ctr + 2048 + (size_t)g*16384;

  // stage packed weight slice global -> LDS (153.6 KB)
  {
    const float4* srcw = reinterpret_cast<const float4*>(Wb + (size_t)s*76800);
    float4* dst = reinterpret_cast<float4*>(smem);
    for (int i = tid; i < 9600; i += 256) dst[i] = srcw[i];
  }
  __syncthreads();

  const float bh0 = bh_g[c0 + colL];
  const float bh1 = bh_g[c0 + 16 + (l & 7)];
  const float bp0 = bp_g[c0 + colL];
  const float bp1 = bp_g[c0 + 16 + (l & 7)];

  // producer scatter offsets into fragment layout (u16 units, within the
  // per-(buf,g,w) region of 48*512 = 24576 u16):
  //   value (row r, col c): hz at kt2=c>>5, hy at kt2+24;
  //   lane=(r&15)+16*((c&31)>>3), el=c&7; r&15 = kq*4+e.
  const int cA  = c0 + colL;                // hz0/hy0 column
  const int cB  = c0 + 16 + (l & 7);        // hz1/hy1 column
  const int foA = (((cA >> 5)*64) + (((cA & 31) >> 3) << 4) + kq*4)*8 + (cA & 7);
  const int foB = (((cB >> 5)*64) + (((cB & 31) >> 3) << 4) + kq*4)*8 + (cB & 7);

  float hz0[4] = {}, hy0[4] = {}, hz1[4] = {}, hy1[4] = {};
  const f16x8* WBp = reinterpret_cast<const f16x8*>(smem);
  // f16x8 bases: WH0=0, WH1=3200, WP0=4800, WP1=8000

  // wave0 wait on ONE dword; monotonic => uniform exit; timeout bails. [r6]
  auto wait_cnt = [&](const u32* cp){
    if (s_dead) return;
    long spins = 0;
    while (__hip_atomic_load(cp, __ATOMIC_RELAXED, __HIP_MEMORY_SCOPE_AGENT) < 32u){
      __builtin_amdgcn_s_sleep(1);
      if (++spins > 3000000L){ if (l == 0) s_dead = 1; break; }
    }
  };

#pragma unroll 1
  for (int t = 0; t < T_STEPS; ++t){
    // x prefetch + convert (independent of the tile) — before the wait
    const float* xb = x + ((size_t)t*BATCH + g*64 + rowA)*64 + kq*8;
    f16x8 xa[2], xs[2];
#pragma unroll
    for (int i = 0; i < 2; ++i){
      const float4 u = *reinterpret_cast<const float4*>(xb + i*32);
      const float4 v = *reinterpret_cast<const float4*>(xb + i*32 + 4);
      xa[i][0]=(_Float16)u.x; xa[i][1]=(_Float16)u.y; xa[i][2]=(_Float16)u.z; xa[i][3]=(_Float16)u.w;
      xa[i][4]=(_Float16)v.x; xa[i][5]=(_Float16)v.y; xa[i][6]=(_Float16)v.z; xa[i][7]=(_Float16)v.w;
      xs[i][0]=(_Float16)(u.x*u.x); xs[i][1]=(_Float16)(u.y*u.y); xs[i][2]=(_Float16)(u.z*u.z); xs[i][3]=(_Float16)(u.w*u.w);
      xs[i][4]=(_Float16)(v.x*v.x); xs[i][5]=(_Float16)(v.y*v.y); xs[i][6]=(_Float16)(v.z*v.z); xs[i][7]=(_Float16)(v.w*v.w);
    }

    if (w == 0){
      if (t > 0) wait_cnt(FL + (size_t)(t-1)*32); // all blocks finished step t-1
      ACQUIRE_L1();                               // one L1 inv per CU per step
    }
    __syncthreads();
    if (s_dead) break;

    // consumer A-fragments: fully contiguous per-wave region, 24-deep MLP
    const u16* fb = st + ((((size_t)(t&1)*8 + g)*4 + w)*48)*512 + (size_t)l*8;

    f32x4 aH0 = {}, aH1 = {}, aP0 = {}, aP1 = {};
    f16x8 av[24];
#pragma unroll
    for (int i = 0; i < 24; ++i) av[i] = *reinterpret_cast<const f16x8*>(fb + (size_t)i*512);

#pragma unroll
    for (int i = 0; i < 2; ++i){              // x K-tiles (kt 0,1), data ready
      aH0 = MFMA16(xa[i], WBp[       i*64 + l ], aH0);
      aH1 = MFMA16(xa[i], WBp[3200 + i*32 + j8], aH1);
      aP0 = MFMA16(xs[i], WBp[4800 + i*64 + l ], aP0);
      aP1 = MFMA16(xs[i], WBp[8000 + i*32 + j8], aP1);
    }
#pragma unroll
    for (int i = 0; i < 24; ++i){             // state K-tiles 2..25; refill 26..49
      f16x8 a = av[i], asq = a*a;
      const int kt = i + 2;
      aH0 = MFMA16(a,   WBp[       kt*64 + l ], aH0);
      aH1 = MFMA16(a,   WBp[3200 + kt*32 + j8], aH1);
      aP0 = MFMA16(asq, WBp[4800 + kt*64 + l ], aP0);
      aP1 = MFMA16(asq, WBp[8000 + kt*32 + j8], aP1);
      av[i] = *reinterpret_cast<const f16x8*>(fb + (size_t)(24+i)*512);
    }
#pragma unroll
    for (int i = 0; i < 24; ++i){             // state K-tiles 26..49
      f16x8 a = av[i], asq = a*a;
      const int kt = i + 26;
      aH0 = MFMA16(a,   WBp[       kt*64 + l ], aH0);
      aH1 = MFMA16(a,   WBp[3200 + kt*32 + j8], aH1);
      aP0 = MFMA16(asq, WBp[4800 + kt*64 + l ], aP0);
      aP1 = MFMA16(asq, WBp[8000 + kt*32 + j8], aP1);
    }

    // local update; scatter into fragment layout of buf (t+1)&1
    u16* wtb = st + ((((size_t)((t+1)&1)*8 + g)*4 + w)*48)*512;
#pragma unroll
    for (int e = 0; e < 4; ++e){
      {
        float hv = ftanh(aH0[e] + bh0), pv = ftanh(aP0[e] + bp0);
        hz0[e] += DTF * (hv + pv);
        hy0[e] += DTF * hz0[e];
        wtb[foA + e*8]         = f2h(hz0[e]);
        wtb[12288 + foA + e*8] = f2h(hy0[e]);   // hy: kt2 += 24 => +24*512 u16
      }
      {
        float hv = ftanh(aH1[e] + bh1), pv = ftanh(aP1[e] + bp1);
        hz1[e] += DTF * (hv + pv);
        hy1[e] += DTF * hz1[e];
        if (v1){
          wtb[foB + e*8]         = f2h(hz1[e]);
          wtb[12288 + foB + e*8] = f2h(hy1[e]);
        }
      }
    }
    asm volatile("s_waitcnt vmcnt(0)" ::: "memory");     // stores in XCD L2
    __syncthreads();
    if (tid == 0)
      __hip_atomic_fetch_add(FL + (size_t)t*32, 1u, __ATOMIC_RELAXED, __HIP_MEMORY_SCOPE_AGENT);
  }

  // final projection: out = hy @ W_r^T + b_r, by slot-0 block of each group.
  // hy fragments are directly readable: kt2 = 24 + ktp in buf0 (T_STEPS even).
  if (s == 0 && !s_dead){
    if (w == 0){ wait_cnt(FL + (size_t)(T_STEPS-1)*32); ACQUIRE_L1(); }
    __syncthreads();
    if (!s_dead){
      const u16* fb = st + (((size_t)g*4 + w)*48)*512 + (size_t)l*8;  // buf0
      const f16x8* Wr8 = reinterpret_cast<const f16x8*>(Wrb);
      f32x4 oc[4] = {};
#pragma unroll
      for (int kt = 0; kt < 24; ++kt){
        f16x8 a = *reinterpret_cast<const f16x8*>(fb + (size_t)(24+kt)*512);
#pragma unroll
        for (int nt = 0; nt < 4; ++nt)
          oc[nt] = MFMA16(a, Wr8[(nt*24 + kt)*64 + l], oc[nt]);
      }
      const int rowC = w*16 + kq*4;
#pragma unroll
      for (int nt = 0; nt < 4; ++nt){
        float bb = br_g[nt*16 + colL];
#pragma unroll
        for (int e = 0; e < 4; ++e)
          out[(size_t)(g*64 + rowC + e)*64 + nt*16 + colL] = oc[nt][e] + bb;
      }
    }
  }
}

extern "C" void kernel_launch(void* const* d_in, const int* in_sizes, int n_in,
                              void* d_out, int out_size, void* d_ws, size_t ws_size,
                              hipStream_t stream) {
  const float* x  = (const float*)d_in[0];
  const float* Wh = (const float*)d_in[1];
  const float* bh = (const float*)d_in[2];
  const float* Wp = (const float*)d_in[3];
  const float* bp = (const float*)d_in[4];
  const float* Wr = (const float*)d_in[5];
  const float* br = (const float*)d_in[6];
  float* out = (float*)d_out;

  if (ws_size < (size_t)WS_NEED) return;    // loud failure: output stays zero
  char* ws = (char*)d_ws;

  u16* Wb  = (u16*)(ws + WB_OFF);
  u16* Wrb = (u16*)(ws + WRB_OFF);
  u16* st  = (u16*)(ws + ST_OFF);
  u32* ctr = (u32*)(ws + CTR_OFF);

  hipMemsetAsync(ws + CTR_OFF, 0, CTR_SZ, stream);   // slot + barrier counters
  hipMemsetAsync(ws + ST_OFF,  0, ST_SZ,  stream);   // zero initial state (t=0)

  prep_weights<<<3296, 64, 0, stream>>>(Wh, Wp, Wr, Wb, Wrb);

  (void)hipFuncSetAttribute(reinterpret_cast<const void*>(rnn_main),
                            hipFuncAttributeMaxDynamicSharedMemorySize, 153600);
  rnn_main<<<256, 256, 153600, stream>>>(x, bh, bp, br, Wb, Wrb, st, ctr, out);
}

// Round 10
// 11965.609 us; speedup vs baseline: 1.0016x; 1.0016x over previous
//
#include <hip/hip_runtime.h>
#include <hip/hip_fp16.h>

typedef _Float16 f16x8 __attribute__((ext_vector_type(8)));
typedef float f32x4 __attribute__((ext_vector_type(4)));
typedef unsigned short u16;
typedef unsigned int u32;

#define T_STEPS 512
#define BATCH   512
#define DTF     0.01f

// workspace layout (bytes)
#define CTR_OFF 0
#define CTR_SZ  1048576                     // slot counters + per-(g,t) barrier counters
#define WB_OFF  (CTR_OFF + CTR_SZ)
#define WB_SZ   (32*2*76800)                // 4,915,200  packed W_h+W_p f16 frags, 32 slices
#define WRB_OFF (WB_OFF + WB_SZ)
#define WRB_SZ  (4*24*64*8*2)               // 98,304     W_r f16 B-frag layout
#define ST_OFF  (WRB_OFF + WRB_SZ)
#define ST_SZ   (2*8*4*48*64*8*2)           // 3,145,728  state in A-FRAGMENT layout
                                            //   [buf][g][w][kt2(48)][lane(64)][8] f16
#define WS_NEED (ST_OFF + ST_SZ)

#define MFMA16(a,b,c) __builtin_amdgcn_mfma_f32_16x16x32_f16((a),(b),(c),0,0,0)

// Intra-XCD acquire: L2 is the coherence point (peers on this XCD by
// construction), L1 is write-through => only L1 can be stale. L1-only inv,
// one wave per CU before the barrier. [Verified rounds 3-9.]
#define ACQUIRE_L1() asm volatile("s_waitcnt vmcnt(0)\n\tbuffer_inv sc0" ::: "memory")

__device__ __forceinline__ u16 f2h(float f){ _Float16 h = (_Float16)f; return *reinterpret_cast<u16*>(&h); }

__device__ __forceinline__ float ftanh(float x){
  float a = fminf(fmaxf(x, -12.f), 12.f);
  float e = __expf(2.f * a);
  return 1.f - 2.f * __builtin_amdgcn_rcpf(e + 1.f);
}

// B-batch machinery: 16 ds_read_b128 per batch (4 kt x {H0,H1,P0,P1}) into a
// named register array; batches double-buffered so batch b+1's reads are in
// flight during batch b's MFMAs (counted lgkmcnt, ~15 reads outstanding).
#define LOADB(BUF, KT0) \
  _Pragma("unroll") \
  for (int j = 0; j < 4; ++j){ \
    BUF[j]      = WBp[((KT0)+j)*64 + l]; \
    BUF[4 + j]  = WBp[3200 + ((KT0)+j)*32 + j8]; \
    BUF[8 + j]  = WBp[4800 + ((KT0)+j)*64 + l]; \
    BUF[12 + j] = WBp[8000 + ((KT0)+j)*32 + j8]; \
  }

#define CONSUME_R(BUF, KT0) /* kts 2..25: consume av[i], refill av[i]<-24+i */ \
  _Pragma("unroll") \
  for (int j = 0; j < 4; ++j){ \
    const int i = (KT0) - 2 + j; \
    f16x8 a = av[i], asq = a*a; \
    aH0 = MFMA16(a,   BUF[j],      aH0); \
    aH1 = MFMA16(a,   BUF[4 + j],  aH1); \
    aP0 = MFMA16(asq, BUF[8 + j],  aP0); \
    aP1 = MFMA16(asq, BUF[12 + j], aP1); \
    av[i] = *reinterpret_cast<const f16x8*>(fb + (size_t)(24 + i)*512); \
  }

#define CONSUME_N(BUF, KT0) /* kts 26..49: consume refilled av, no refill */ \
  _Pragma("unroll") \
  for (int j = 0; j < 4; ++j){ \
    const int i = (KT0) - 26 + j; \
    f16x8 a = av[i], asq = a*a; \
    aH0 = MFMA16(a,   BUF[j],      aH0); \
    aH1 = MFMA16(a,   BUF[4 + j],  aH1); \
    aP0 = MFMA16(asq, BUF[8 + j],  aP0); \
    aP1 = MFMA16(asq, BUF[12 + j], aP1); \
  }

// Packed per-slice weight image (u16 units), slice s owns cols [s*24, s*24+24)
// of BOTH matrices (identity K order: k<64 -> x, 64..831 -> hz, 832.. -> hy):
//   base = s*76800 ; mat m in {0=W_h,1=W_p}: mbase = base + m*38400
//   nt0 full frags : mbase + kt*512 + l*8          (l=0..63)  col = s*24 + (l&15),   k = kt*32+(l>>4)*8
//   nt1 half frags : mbase + 25600 + kt*256 + j*8  (j=0..31)  col = s*24+16 + (j&7), k = kt*32+(j>>3)*8
// Wrb[nt(4)][kt(24)][lane(64)][8] for the final projection.
__global__ __launch_bounds__(64) void prep_weights(const float* __restrict__ Wh,
                                                   const float* __restrict__ Wp,
                                                   const float* __restrict__ Wr,
                                                   u16* __restrict__ Wb, u16* __restrict__ Wrb){
  int b = blockIdx.x, l = threadIdx.x;
  if (b < 3200){
    int s = b / 100, rem = b % 100;
    int m = rem / 50, kt = rem % 50;
    const float* W = m ? Wp : Wh;
    size_t mbase = (size_t)s*76800 + (size_t)m*38400;
    {
      int col = s*24 + (l & 15), k = kt*32 + (l >> 4)*8;
      const float* src = W + (size_t)col*1600 + k;
      f16x8 o;
#pragma unroll
      for (int e = 0; e < 8; ++e) o[e] = (_Float16)src[e];
      *reinterpret_cast<f16x8*>(Wb + mbase + (size_t)kt*512 + (size_t)l*8) = o;
    }
    if (l < 32){
      int col = s*24 + 16 + (l & 7), k = kt*32 + (l >> 3)*8;
      const float* src = W + (size_t)col*1600 + k;
      f16x8 o;
#pragma unroll
      for (int e = 0; e < 8; ++e) o[e] = (_Float16)src[e];
      *reinterpret_cast<f16x8*>(Wb + mbase + 25600 + (size_t)kt*256 + (size_t)l*8) = o;
    }
  } else {
    int b2 = b - 3200;                      // 0..95
    int nt = b2 / 24, kt = b2 % 24;
    int c = nt*16 + (l & 15), k = kt*32 + (l >> 4)*8;
    const float* src = Wr + (size_t)c*768 + k;
    f16x8 o;
#pragma unroll
    for (int e = 0; e < 8; ++e) o[e] = (_Float16)src[e];
    *reinterpret_cast<f16x8*>(Wrb + ((size_t)b2*64 + l)*8) = o;
  }
}

// grid = 256 x 256. Group = PHYSICAL XCD (HW_REG_XCC_ID), slot via atomicAdd:
// 32 blocks/XCD (1 block/CU by LDS). Slot s owns out-cols [s*24,+24) of BOTH
// W_h/W_p. State in A-fragment layout (r9). THIS ROUND: LDS B-reads batched
// 16-deep + register-double-buffered — attacks the exposed ds_read latency at
// 1 wave/SIMD that r3-r9 cross-round arithmetic identified as the real stall.
__global__ __launch_bounds__(256, 1) void rnn_main(
    const float* __restrict__ x, const float* __restrict__ bh_g, const float* __restrict__ bp_g,
    const float* __restrict__ br_g, const u16* __restrict__ Wb, const u16* __restrict__ Wrb,
    u16* __restrict__ st, u32* __restrict__ ctr, float* __restrict__ out)
{
  extern __shared__ u16 smem[];             // packed weight slice, 153,600 B
  __shared__ int s_dead, s_slot, s_xcd;

  const int tid = threadIdx.x;
  if (tid == 0){
    s_dead = 0;
    u32 xcd;
    asm volatile("s_getreg_b32 %0, hwreg(HW_REG_XCC_ID)" : "=s"(xcd));
    xcd &= 7u;
    s_xcd  = (int)xcd;
    s_slot = (int)atomicAdd(ctr + xcd, 1u); // device-scope, ctr pre-zeroed
  }
  __syncthreads();
  const int g = s_xcd;
  const int s = s_slot;
  if (s >= 32) return;

  const int c0   = s * 24;
  const int l    = tid & 63;
  const int w    = tid >> 6;
  const int colL = l & 15;
  const int kq   = l >> 4;
  const int j8   = kq*8 + (l & 7);          // nt1 half-frag index
  const int rowA = w*16 + colL;             // A-frag row for x loads
  const bool v1  = (colL < 8);              // nt1 validity

  // per-(g,t) barrier counters: ctr[2048 + g*16384 + t*32], 128B stride  [r6]
  u32* FL = ctr + 2048 + (size_t)g*16384;

  // stage packed weight slice global -> LDS (153.6 KB)
  {
    const float4* srcw = reinterpret_cast<const float4*>(Wb + (size_t)s*76800);
    float4* dst = reinterpret_cast<float4*>(smem);
    for (int i = tid; i < 9600; i += 256) dst[i] = srcw[i];
  }
  __syncthreads();

  const float bh0 = bh_g[c0 + colL];
  const float bh1 = bh_g[c0 + 16 + (l & 7)];
  const float bp0 = bp_g[c0 + colL];
  const float bp1 = bp_g[c0 + 16 + (l & 7)];

  // producer scatter offsets into fragment layout (u16 units):
  //   value (row r, col c): hz at kt2=c>>5, hy at kt2+24;
  //   lane=(r&15)+16*((c&31)>>3), el=c&7; r&15 = kq*4+e.
  const int cA  = c0 + colL;                // hz0/hy0 column
  const int cB  = c0 + 16 + (l & 7);        // hz1/hy1 column
  const int foA = (((cA >> 5)*64) + (((cA & 31) >> 3) << 4) + kq*4)*8 + (cA & 7);
  const int foB = (((cB >> 5)*64) + (((cB & 31) >> 3) << 4) + kq*4)*8 + (cB & 7);

  float hz0[4] = {}, hy0[4] = {}, hz1[4] = {}, hy1[4] = {};
  const f16x8* WBp = reinterpret_cast<const f16x8*>(smem);
  // f16x8 bases: WH0=0, WH1=3200, WP0=4800, WP1=8000

  // wave0 wait on ONE dword; monotonic => uniform exit; timeout bails. [r6]
  auto wait_cnt = [&](const u32* cp){
    if (s_dead) return;
    long spins = 0;
    while (__hip_atomic_load(cp, __ATOMIC_RELAXED, __HIP_MEMORY_SCOPE_AGENT) < 32u){
      __builtin_amdgcn_s_sleep(1);
      if (++spins > 3000000L){ if (l == 0) s_dead = 1; break; }
    }
  };

#pragma unroll 1
  for (int t = 0; t < T_STEPS; ++t){
    // x prefetch + convert (independent of the tile) — before the wait
    const float* xb = x + ((size_t)t*BATCH + g*64 + rowA)*64 + kq*8;
    f16x8 xa[2], xs[2];
#pragma unroll
    for (int i = 0; i < 2; ++i){
      const float4 u = *reinterpret_cast<const float4*>(xb + i*32);
      const float4 v = *reinterpret_cast<const float4*>(xb + i*32 + 4);
      xa[i][0]=(_Float16)u.x; xa[i][1]=(_Float16)u.y; xa[i][2]=(_Float16)u.z; xa[i][3]=(_Float16)u.w;
      xa[i][4]=(_Float16)v.x; xa[i][5]=(_Float16)v.y; xa[i][6]=(_Float16)v.z; xa[i][7]=(_Float16)v.w;
      xs[i][0]=(_Float16)(u.x*u.x); xs[i][1]=(_Float16)(u.y*u.y); xs[i][2]=(_Float16)(u.z*u.z); xs[i][3]=(_Float16)(u.w*u.w);
      xs[i][4]=(_Float16)(v.x*v.x); xs[i][5]=(_Float16)(v.y*v.y); xs[i][6]=(_Float16)(v.z*v.z); xs[i][7]=(_Float16)(v.w*v.w);
    }

    if (w == 0){
      if (t > 0) wait_cnt(FL + (size_t)(t-1)*32); // all blocks finished step t-1
      ACQUIRE_L1();                               // one L1 inv per CU per step
    }
    __syncthreads();
    if (s_dead) break;

    // consumer A-fragments: contiguous per-wave region, 24-deep (vmcnt path)
    const u16* fb = st + ((((size_t)(t&1)*8 + g)*4 + w)*48)*512 + (size_t)l*8;

    f32x4 aH0 = {}, aH1 = {}, aP0 = {}, aP1 = {};
    f16x8 av[24];
#pragma unroll
    for (int i = 0; i < 24; ++i) av[i] = *reinterpret_cast<const f16x8*>(fb + (size_t)i*512);

    // x B-frags (kt 0,1) + first state batch issued together (lgkmcnt path)
    f16x8 bx[8];
#pragma unroll
    for (int j = 0; j < 2; ++j){
      bx[j]     = WBp[j*64 + l];
      bx[2 + j] = WBp[3200 + j*32 + j8];
      bx[4 + j] = WBp[4800 + j*64 + l];
      bx[6 + j] = WBp[8000 + j*32 + j8];
    }
    f16x8 b0[16], b1[16];
    LOADB(b0, 2);
#pragma unroll
    for (int i2 = 0; i2 < 2; ++i2){           // x K-tiles, data ready
      aH0 = MFMA16(xa[i2], bx[i2],     aH0);
      aH1 = MFMA16(xa[i2], bx[2 + i2], aH1);
      aP0 = MFMA16(xs[i2], bx[4 + i2], aP0);
      aP1 = MFMA16(xs[i2], bx[6 + i2], aP1);
    }
    // 12 state batches, register-double-buffered (load b+1 before MFMA b)
    LOADB(b1, 6);  CONSUME_R(b0, 2);
    LOADB(b0, 10); CONSUME_R(b1, 6);
    LOADB(b1, 14); CONSUME_R(b0, 10);
    LOADB(b0, 18); CONSUME_R(b1, 14);
    LOADB(b1, 22); CONSUME_R(b0, 18);
    LOADB(b0, 26); CONSUME_R(b1, 22);
    LOADB(b1, 30); CONSUME_N(b0, 26);
    LOADB(b0, 34); CONSUME_N(b1, 30);
    LOADB(b1, 38); CONSUME_N(b0, 34);
    LOADB(b0, 42); CONSUME_N(b1, 38);
    LOADB(b1, 46); CONSUME_N(b0, 42);
                   CONSUME_N(b1, 46);

    // local update; scatter into fragment layout of buf (t+1)&1
    u16* wtb = st + ((((size_t)((t+1)&1)*8 + g)*4 + w)*48)*512;
#pragma unroll
    for (int e = 0; e < 4; ++e){
      {
        float hv = ftanh(aH0[e] + bh0), pv = ftanh(aP0[e] + bp0);
        hz0[e] += DTF * (hv + pv);
        hy0[e] += DTF * hz0[e];
        wtb[foA + e*8]         = f2h(hz0[e]);
        wtb[12288 + foA + e*8] = f2h(hy0[e]);   // hy: kt2 += 24 => +24*512 u16
      }
      {
        float hv = ftanh(aH1[e] + bh1), pv = ftanh(aP1[e] + bp1);
        hz1[e] += DTF * (hv + pv);
        hy1[e] += DTF * hz1[e];
        if (v1){
          wtb[foB + e*8]         = f2h(hz1[e]);
          wtb[12288 + foB + e*8] = f2h(hy1[e]);
        }
      }
    }
    asm volatile("s_waitcnt vmcnt(0)" ::: "memory");     // stores in XCD L2
    __syncthreads();
    if (tid == 0)
      __hip_atomic_fetch_add(FL + (size_t)t*32, 1u, __ATOMIC_RELAXED, __HIP_MEMORY_SCOPE_AGENT);
  }

  // final projection: out = hy @ W_r^T + b_r, by slot-0 block of each group.
  // hy fragments are directly readable: kt2 = 24 + ktp in buf0 (T_STEPS even).
  if (s == 0 && !s_dead){
    if (w == 0){ wait_cnt(FL + (size_t)(T_STEPS-1)*32); ACQUIRE_L1(); }
    __syncthreads();
    if (!s_dead){
      const u16* fb = st + (((size_t)g*4 + w)*48)*512 + (size_t)l*8;  // buf0
      const f16x8* Wr8 = reinterpret_cast<const f16x8*>(Wrb);
      f32x4 oc[4] = {};
#pragma unroll
      for (int kt = 0; kt < 24; ++kt){
        f16x8 a = *reinterpret_cast<const f16x8*>(fb + (size_t)(24+kt)*512);
#pragma unroll
        for (int nt = 0; nt < 4; ++nt)
          oc[nt] = MFMA16(a, Wr8[(nt*24 + kt)*64 + l], oc[nt]);
      }
      const int rowC = w*16 + kq*4;
#pragma unroll
      for (int nt = 0; nt < 4; ++nt){
        float bb = br_g[nt*16 + colL];
#pragma unroll
        for (int e = 0; e < 4; ++e)
          out[(size_t)(g*64 + rowC + e)*64 + nt*16 + colL] = oc[nt][e] + bb;
      }
    }
  }
}

extern "C" void kernel_launch(void* const* d_in, const int* in_sizes, int n_in,
                              void* d_out, int out_size, void* d_ws, size_t ws_size,
                              hipStream_t stream) {
  const float* x  = (const float*)d_in[0];
  const float* Wh = (const float*)d_in[1];
  const float* bh = (const float*)d_in[2];
  const float* Wp = (const float*)d_in[3];
  const float* bp = (const float*)d_in[4];
  const float* Wr = (const float*)d_in[5];
  const float* br = (const float*)d_in[6];
  float* out = (float*)d_out;

  if (ws_size < (size_t)WS_NEED) return;    // loud failure: output stays zero
  char* ws = (char*)d_ws;

  u16* Wb  = (u16*)(ws + WB_OFF);
  u16* Wrb = (u16*)(ws + WRB_OFF);
  u16* st  = (u16*)(ws + ST_OFF);
  u32* ctr = (u32*)(ws + CTR_OFF);

  hipMemsetAsync(ws + CTR_OFF, 0, CTR_SZ, stream);   // slot + barrier counters
  hipMemsetAsync(ws + ST_OFF,  0, ST_SZ,  stream);   // zero initial state (t=0)

  prep_weights<<<3296, 64, 0, stream>>>(Wh, Wp, Wr, Wb, Wrb);

  (void)hipFuncSetAttribute(reinterpret_cast<const void*>(rnn_main),
                            hipFuncAttributeMaxDynamicSharedMemorySize, 153600);
  rnn_main<<<256, 256, 153600, stream>>>(x, bh, bp, br, Wb, Wrb, st, ctr, out);
}

// Round 12
// 7681.242 us; speedup vs baseline: 1.5602x; 1.5578x over previous
//
#include <hip/hip_runtime.h>
#include <hip/hip_fp16.h>

typedef _Float16 f16x8 __attribute__((ext_vector_type(8)));
typedef float f32x4 __attribute__((ext_vector_type(4)));
typedef float f32x16 __attribute__((ext_vector_type(16)));
typedef unsigned short u16;
typedef unsigned int u32;

#define T_STEPS 512
#define BATCH   512
#define DTF     0.01f

// workspace layout (bytes)
#define CTR_OFF 0
#define CTR_SZ  1048576                     // slot counters + per-(g,t) barrier counters
#define WB_OFF  (CTR_OFF + CTR_SZ)
#define WB_SZ   (32*200*384*2)              // 4,915,200  [slice][mat*100+unit][384 u16] 32x32 B-frags
#define WRB_OFF (WB_OFF + WB_SZ)
#define WRB_SZ  (4*24*64*8*2)               // 98,304     W_r f16 B-frag layout (16x16x32)
#define ST_OFF  (WRB_OFF + WRB_SZ)
#define ST_SZ   (2*8*64*1536*2)             // 3,145,728  state [buf][g][row 64][k' 1536] f16
#define WS_NEED (ST_OFF + ST_SZ)

#define MFMA32(a,b,c) __builtin_amdgcn_mfma_f32_32x32x16_f16((a),(b),(c),0,0,0)
#define MFMA16(a,b,c) __builtin_amdgcn_mfma_f32_16x16x32_f16((a),(b),(c),0,0,0)

// Intra-XCD acquire: L2 is the coherence point, L1 write-through => L1-only
// invalidate; one wave per CU. [Verified rounds 3-10.]
#define ACQUIRE_L1() asm volatile("s_waitcnt vmcnt(0)\n\tbuffer_inv sc0" ::: "memory")

__device__ __forceinline__ u16 f2h(float f){ _Float16 h = (_Float16)f; return *reinterpret_cast<u16*>(&h); }

__device__ __forceinline__ float ftanh(float x){
  float a = fminf(fmaxf(x, -12.f), 12.f);
  float e = __expf(2.f * a);
  return 1.f - 2.f * __builtin_amdgcn_rcpf(e + 1.f);
}

// ---- 32x32x16 fragment maps (standard gfx950 mapping; absmax will verify) ----
// A (32x16): lane holds A[l&31][(l>>5)*8 + e]
// B (16x32): lane holds B[(l>>5)*8 + e][l&31]
// C (32x32): lane covers col = l&31, rows = (e&3) + 8*(e>>2) + 4*(l>>5)
//
// LDS B storage per (slice s, mat m2, unit u): 24 valid cols x 2 k-halves =
// 48 granules of 16B = 768B. Granule g = col*2 + kh placed with XOR swizzle:
// r=g>>3, c=g&7 -> offset r*128B + ((c^(r&7))*16B) => conflict-free b128 reads.
// Lanes with col>=24 alias col-24 (broadcast; results discarded).

__global__ __launch_bounds__(64) void prep_weights(const float* __restrict__ Wh,
                                                   const float* __restrict__ Wp,
                                                   const float* __restrict__ Wr,
                                                   u16* __restrict__ Wb, u16* __restrict__ Wrb){
  int b = blockIdx.x, l = threadIdx.x;
  if (b < 6400){
    int s = b / 200, r2 = b % 200;
    int m2 = r2 / 100, u = r2 % 100;
    if (l < 48){
      int c = l >> 1, kh = l & 1;
      int gg = c*2 + kh, rr = gg >> 3, cc = gg & 7;
      size_t dst = (size_t)s*76800 + (size_t)(m2*100 + u)*384 + (size_t)rr*64 + (size_t)((cc ^ (rr & 7))*8);
      const float* W = m2 ? Wp : Wh;
      const float* src = W + (size_t)(s*24 + c)*1600 + u*16 + kh*8;
      f16x8 o;
#pragma unroll
      for (int e = 0; e < 8; ++e) o[e] = (_Float16)src[e];
      *reinterpret_cast<f16x8*>(Wb + dst) = o;
    }
  } else {
    int b2 = b - 6400;                      // 0..95  (W_r, 16x16x32 B-frags)
    int nt = b2 / 24, kt = b2 % 24;
    int c = nt*16 + (l & 15), k = kt*32 + (l >> 4)*8;
    const float* src = Wr + (size_t)c*768 + k;
    f16x8 o;
#pragma unroll
    for (int e = 0; e < 8; ++e) o[e] = (_Float16)src[e];
    *reinterpret_cast<f16x8*>(Wrb + ((size_t)b2*64 + l)*8) = o;
  }
}

// grid = 256 x 256. Group = PHYSICAL XCD (HW_REG_XCC_ID), slot via atomicAdd:
// 32 blocks/XCD. Slot s owns out-cols [s*24,+24) of BOTH W_h/W_p.
// Wave (m = w&1, p = w>>1): m-tile rows [m*32,+32), K-half p (units p? 50-99
// : 0-49; units 0-3 are x). 32x32x16 MFMA halves LDS B-port traffic (the
// r10-identified binding resource). Partials reduced via 8KB LDS scratch;
// waves 0/1 do the update. Sync = r6 verified single-dword counter.
__global__ __launch_bounds__(256, 1) void rnn_main(
    const float* __restrict__ x, const float* __restrict__ bh_g, const float* __restrict__ bp_g,
    const float* __restrict__ br_g, const u16* __restrict__ Wb, const u16* __restrict__ Wrb,
    u16* __restrict__ st, u32* __restrict__ ctr, float* __restrict__ out)
{
  extern __shared__ u16 smem[];             // [0,153600): B-frags; [153600,161792): reduce scratch
  __shared__ int s_dead, s_slot, s_xcd;

  const int tid = threadIdx.x;
  if (tid == 0){
    s_dead = 0;
    u32 xcd;
    asm volatile("s_getreg_b32 %0, hwreg(HW_REG_XCC_ID)" : "=s"(xcd));
    xcd &= 7u;
    s_xcd  = (int)xcd;
    s_slot = (int)atomicAdd(ctr + xcd, 1u); // device-scope, ctr pre-zeroed
  }
  __syncthreads();
  const int gx = s_xcd;
  const int s  = s_slot;
  if (s >= 32) return;

  const int c0   = s * 24;
  const int l    = tid & 63;
  const int w    = tid >> 6;
  const int m    = w & 1;                   // m-tile (rows m*32..+32)
  const int p    = w >> 1;                  // K-half
  const int colW = l & 31;                  // C col / A row-in-tile
  const int khB  = l >> 5;                  // k-half within unit
  const bool validC = (colW < 24);
  const int colB = validC ? colW : colW - 24;
  const int gran = colB*2 + khB;
  const int grr  = gran >> 3, gcc = gran & 7;
  const int bfi  = grr*8 + (gcc ^ (grr & 7));   // f16x8 index within a 768B unit-block

  // per-(g,t) barrier counters: ctr[2048 + g*16384 + t*32]  [r6 verified]
  u32* FL = ctr + 2048 + (size_t)gx*16384;

  // stage packed weight slice global -> LDS (153.6 KB)
  {
    const float4* srcw = reinterpret_cast<const float4*>(Wb + (size_t)s*76800);
    float4* dst = reinterpret_cast<float4*>(smem);
    for (int i = tid; i < 9600; i += 256) dst[i] = srcw[i];
  }
  __syncthreads();

  const f16x8* WBp = reinterpret_cast<const f16x8*>(smem);
  float* scr = reinterpret_cast<float*>(smem + 76800);   // 8KB reduce scratch

  // x-unit B-frags (units 0..3, both mats) held permanently in registers (p==0)
  f16x8 xbh[4], xbp[4];
  if (p == 0){
#pragma unroll
    for (int u = 0; u < 4; ++u){ xbh[u] = WBp[u*48 + bfi]; xbp[u] = WBp[(100+u)*48 + bfi]; }
  }

  const int dcol = c0 + (validC ? colW : 0);
  const float bhv = bh_g[dcol];
  const float bpv = bp_g[dcol];

  float hz[16] = {}, hy[16] = {};           // fp32 master state (p==0 waves)

  auto wait_cnt = [&](const u32* cp){
    if (s_dead) return;
    long spins = 0;
    while (__hip_atomic_load(cp, __ATOMIC_RELAXED, __HIP_MEMORY_SCOPE_AGENT) < 32u){
      __builtin_amdgcn_s_sleep(1);
      if (++spins > 1000000L){ if (l == 0) s_dead = 1; break; }
    }
  };

#define STATE_LOOP(U0c, NUc) do { \
    f16x8 av[4]; \
    _Pragma("unroll") \
    for (int i = 0; i < 4; ++i) av[i] = *reinterpret_cast<const f16x8*>(stb + (size_t)((U0c)-4+i)*16); \
    _Pragma("unroll") \
    for (int i = 0; i < (NUc); ++i){ \
      f16x8 a = av[i & 3]; \
      if (i + 4 < (NUc)) av[i & 3] = *reinterpret_cast<const f16x8*>(stb + (size_t)((U0c)+i)*16); \
      f16x8 bh8 = WBp[((U0c)+i)*48 + bfi]; \
      f16x8 bp8 = WBp[(100+(U0c)+i)*48 + bfi]; \
      f16x8 asq = a*a; \
      accH = MFMA32(a,   bh8, accH); \
      accP = MFMA32(asq, bp8, accP); \
    } } while (0)

#pragma unroll 1
  for (int t = 0; t < T_STEPS; ++t){
    f32x16 accH = {}, accP = {};

    // x contribution (units 0..3): independent of the tile — done pre-wait
    if (p == 0){
      const float* xb = x + ((size_t)t*BATCH + gx*64 + m*32 + colW)*64 + khB*8;
#pragma unroll
      for (int u = 0; u < 4; ++u){
        const float4 uu = *reinterpret_cast<const float4*>(xb + u*16);
        const float4 vv = *reinterpret_cast<const float4*>(xb + u*16 + 4);
        f16x8 xa8, xs8;
        xa8[0]=(_Float16)uu.x; xa8[1]=(_Float16)uu.y; xa8[2]=(_Float16)uu.z; xa8[3]=(_Float16)uu.w;
        xa8[4]=(_Float16)vv.x; xa8[5]=(_Float16)vv.y; xa8[6]=(_Float16)vv.z; xa8[7]=(_Float16)vv.w;
        xs8[0]=(_Float16)(uu.x*uu.x); xs8[1]=(_Float16)(uu.y*uu.y); xs8[2]=(_Float16)(uu.z*uu.z); xs8[3]=(_Float16)(uu.w*uu.w);
        xs8[4]=(_Float16)(vv.x*vv.x); xs8[5]=(_Float16)(vv.y*vv.y); xs8[6]=(_Float16)(vv.z*vv.z); xs8[7]=(_Float16)(vv.w*vv.w);
        accH = MFMA32(xa8, xbh[u], accH);
        accP = MFMA32(xs8, xbp[u], accP);
      }
    }

    if (w == 0){
      if (t > 0) wait_cnt(FL + (size_t)(t-1)*32);
      ACQUIRE_L1();
    }
    __syncthreads();
    if (s_dead) break;

    // state A-frags: lane reads 16B at row = m*32+colW, k-offset khB*8 (plain layout)
    const u16* stb = st + ((((size_t)(t&1)*8 + gx)*64) + m*32 + colW)*1536 + khB*8;
    if (p == 0) STATE_LOOP(4, 46); else STATE_LOOP(50, 50);

    // cross-wave K-half reduce through LDS scratch (w2->w0, w3->w1)
    if (p == 1){
#pragma unroll
      for (int e = 0; e < 16; ++e) scr[((size_t)m*64 + l)*16 + e] = accH[e];
    }
    __syncthreads();
    if (p == 0){
#pragma unroll
      for (int e = 0; e < 16; ++e) accH[e] += scr[((size_t)m*64 + l)*16 + e];
    }
    __syncthreads();
    if (p == 1){
#pragma unroll
      for (int e = 0; e < 16; ++e) scr[((size_t)m*64 + l)*16 + e] = accP[e];
    }
    __syncthreads();
    if (p == 0){
#pragma unroll
      for (int e = 0; e < 16; ++e) accP[e] += scr[((size_t)m*64 + l)*16 + e];
    }

    // update + store (waves 0/1 only; lane covers col=colW, 16 rows)
    if (p == 0){
      u16* wtb = st + (((size_t)((t+1)&1)*8 + gx)*64)*1536;
#pragma unroll
      for (int e = 0; e < 16; ++e){
        float hv = ftanh(accH[e] + bhv);
        float pv = ftanh(accP[e] + bpv);
        hz[e] += DTF * (hv + pv);
        hy[e] += DTF * hz[e];
        if (validC){
          int row = m*32 + (e & 3) + 8*(e >> 2) + 4*khB;
          wtb[(size_t)row*1536 + dcol]       = f2h(hz[e]);
          wtb[(size_t)row*1536 + 768 + dcol] = f2h(hy[e]);
        }
      }
      asm volatile("s_waitcnt vmcnt(0)" ::: "memory");   // stores visible in XCD L2
    }
    __syncthreads();
    if (tid == 0)
      __hip_atomic_fetch_add(FL + (size_t)t*32, 1u, __ATOMIC_RELAXED, __HIP_MEMORY_SCOPE_AGENT);
  }
#undef STATE_LOOP

  // final projection: out = hy @ W_r^T + b_r, slot-0 block (16x16x32 path)
  if (s == 0 && !s_dead){
    if (w == 0){ wait_cnt(FL + (size_t)(T_STEPS-1)*32); ACQUIRE_L1(); }
    __syncthreads();
    if (!s_dead){
      const int colL = l & 15, kq4 = l >> 4;
      const u16* hyb = st + (((size_t)gx*64) + w*16 + colL)*1536 + 768 + kq4*8;  // buf0
      const f16x8* Wr8 = reinterpret_cast<const f16x8*>(Wrb);
      f32x4 oc[4] = {};
#pragma unroll
      for (int kt = 0; kt < 24; ++kt){
        f16x8 a = *reinterpret_cast<const f16x8*>(hyb + (size_t)kt*32);
#pragma unroll
        for (int nt = 0; nt < 4; ++nt)
          oc[nt] = MFMA16(a, Wr8[(nt*24 + kt)*64 + l], oc[nt]);
      }
      const int rowC = w*16 + kq4*4;
#pragma unroll
      for (int nt = 0; nt < 4; ++nt){
        float bb = br_g[nt*16 + colL];
#pragma unroll
        for (int e = 0; e < 4; ++e)
          out[(size_t)(gx*64 + rowC + e)*64 + nt*16 + colL] = oc[nt][e] + bb;
      }
    }
  }
}

extern "C" void kernel_launch(void* const* d_in, const int* in_sizes, int n_in,
                              void* d_out, int out_size, void* d_ws, size_t ws_size,
                              hipStream_t stream) {
  const float* x  = (const float*)d_in[0];
  const float* Wh = (const float*)d_in[1];
  const float* bh = (const float*)d_in[2];
  const float* Wp = (const float*)d_in[3];
  const float* bp = (const float*)d_in[4];
  const float* Wr = (const float*)d_in[5];
  const float* br = (const float*)d_in[6];
  float* out = (float*)d_out;

  if (ws_size < (size_t)WS_NEED) return;    // loud failure: output stays zero
  char* ws = (char*)d_ws;

  u16* Wb  = (u16*)(ws + WB_OFF);
  u16* Wrb = (u16*)(ws + WRB_OFF);
  u16* st  = (u16*)(ws + ST_OFF);
  u32* ctr = (u32*)(ws + CTR_OFF);

  hipMemsetAsync(ws + CTR_OFF, 0, CTR_SZ, stream);   // slot + barrier counters
  hipMemsetAsync(ws + ST_OFF,  0, ST_SZ,  stream);   // zero initial state (t=0)

  prep_weights<<<6496, 64, 0, stream>>>(Wh, Wp, Wr, Wb, Wrb);

  (void)hipFuncSetAttribute(reinterpret_cast<const void*>(rnn_main),
                            hipFuncAttributeMaxDynamicSharedMemorySize, 161792);
  rnn_main<<<256, 256, 161792, stream>>>(x, bh, bp, br, Wb, Wrb, st, ctr, out);
}

// Round 14
// 7077.806 us; speedup vs baseline: 1.6933x; 1.0853x over previous
//
#include <hip/hip_runtime.h>
#include <hip/hip_fp16.h>

typedef _Float16 f16x8 __attribute__((ext_vector_type(8)));
typedef float f32x4 __attribute__((ext_vector_type(4)));
typedef float f32x16 __attribute__((ext_vector_type(16)));
typedef unsigned short u16;
typedef unsigned int u32;

#define T_STEPS 512
#define BATCH   512
#define DTF     0.01f

// workspace layout (bytes)
#define CTR_OFF 0
#define CTR_SZ  1048576                     // slot counters + per-(g,t) barrier counters
#define WB_OFF  (CTR_OFF + CTR_SZ)
#define WB_SZ   (32*200*384*2)              // 4,915,200  [slice][mat*100+unit][384 u16] 32x32 B-frags
#define WRB_OFF (WB_OFF + WB_SZ)
#define WRB_SZ  (4*24*64*8*2)               // 98,304     W_r f16 B-frag layout (16x16x32)
#define ST_OFF  (WRB_OFF + WRB_SZ)
#define ST_SZ   (2*8*64*1536*2)             // 3,145,728  state [buf][g][row 64][k' 1536] f16
#define WS_NEED (ST_OFF + ST_SZ)

#define MFMA32(a,b,c) __builtin_amdgcn_mfma_f32_32x32x16_f16((a),(b),(c),0,0,0)
#define MFMA16(a,b,c) __builtin_amdgcn_mfma_f32_16x16x32_f16((a),(b),(c),0,0,0)

// Intra-XCD acquire: L2 is the coherence point, L1 write-through => L1-only
// invalidate; one wave per CU. [Verified rounds 3-12.]
#define ACQUIRE_L1() asm volatile("s_waitcnt vmcnt(0)\n\tbuffer_inv sc0" ::: "memory")

__device__ __forceinline__ u16 f2h(float f){ _Float16 h = (_Float16)f; return *reinterpret_cast<u16*>(&h); }

__device__ __forceinline__ float ftanh(float x){
  float a = fminf(fmaxf(x, -12.f), 12.f);
  float e = __expf(2.f * a);
  return 1.f - 2.f * __builtin_amdgcn_rcpf(e + 1.f);
}

// ---- 32x32x16 fragment maps [verified r12: absmax 0.03125] ----
// A (32x16): lane holds A[l&31][(l>>5)*8 + e]
// B (16x32): lane holds B[(l>>5)*8 + e][l&31]
// C (32x32): lane covers col = l&31, rows = (e&3) + 8*(e>>2) + 4*(l>>5)
//
// LDS B storage per (slice s, mat m2, unit u): 48 granules of 16B, XOR-swizzled
// (balanced: 6 granules per bank-quad). Lanes col>=24 alias col-24 (broadcast).

__global__ __launch_bounds__(64) void prep_weights(const float* __restrict__ Wh,
                                                   const float* __restrict__ Wp,
                                                   const float* __restrict__ Wr,
                                                   u16* __restrict__ Wb, u16* __restrict__ Wrb){
  int b = blockIdx.x, l = threadIdx.x;
  if (b < 6400){
    int s = b / 200, r2 = b % 200;
    int m2 = r2 / 100, u = r2 % 100;
    if (l < 48){
      int c = l >> 1, kh = l & 1;
      int gg = c*2 + kh, rr = gg >> 3, cc = gg & 7;
      size_t dst = (size_t)s*76800 + (size_t)(m2*100 + u)*384 + (size_t)rr*64 + (size_t)((cc ^ (rr & 7))*8);
      const float* W = m2 ? Wp : Wh;
      const float* src = W + (size_t)(s*24 + c)*1600 + u*16 + kh*8;
      f16x8 o;
#pragma unroll
      for (int e = 0; e < 8; ++e) o[e] = (_Float16)src[e];
      *reinterpret_cast<f16x8*>(Wb + dst) = o;
    }
  } else {
    int b2 = b - 6400;                      // 0..95  (W_r, 16x16x32 B-frags)
    int nt = b2 / 24, kt = b2 % 24;
    int c = nt*16 + (l & 15), k = kt*32 + (l >> 4)*8;
    const float* src = Wr + (size_t)c*768 + k;
    f16x8 o;
#pragma unroll
    for (int e = 0; e < 8; ++e) o[e] = (_Float16)src[e];
    *reinterpret_cast<f16x8*>(Wrb + ((size_t)b2*64 + l)*8) = o;
  }
}

// grid = 256 x 256. Group = PHYSICAL XCD (HW_REG_XCC_ID), slot via atomicAdd:
// 32 blocks/XCD. Slot s owns out-cols [s*24,+24) of BOTH W_h/W_p.
// Wave (m = w&1, p = w>>1): m-tile rows [m*32,+32), K-half p. 32x32x16 MFMA
// (r12: halved LDS B-port traffic, 12.0->7.7ms). THIS ROUND: e-major reduce
// scratch — r12's (m*64+l)*16+e layout put all 64 lanes on 2 banks (32-way,
// 3840 conflict-cy/CU/step measured); e*128+m*64+l gives stride-1 lanes
// (2-way alias only, free). Sync = r6 verified single-dword counter.
__global__ __launch_bounds__(256, 1) void rnn_main(
    const float* __restrict__ x, const float* __restrict__ bh_g, const float* __restrict__ bp_g,
    const float* __restrict__ br_g, const u16* __restrict__ Wb, const u16* __restrict__ Wrb,
    u16* __restrict__ st, u32* __restrict__ ctr, float* __restrict__ out)
{
  extern __shared__ u16 smem[];             // [0,153600): B-frags; [153600,161792): reduce scratch
  __shared__ int s_dead, s_slot, s_xcd;

  const int tid = threadIdx.x;
  if (tid == 0){
    s_dead = 0;
    u32 xcd;
    asm volatile("s_getreg_b32 %0, hwreg(HW_REG_XCC_ID)" : "=s"(xcd));
    xcd &= 7u;
    s_xcd  = (int)xcd;
    s_slot = (int)atomicAdd(ctr + xcd, 1u); // device-scope, ctr pre-zeroed
  }
  __syncthreads();
  const int gx = s_xcd;
  const int s  = s_slot;
  if (s >= 32) return;

  const int c0   = s * 24;
  const int l    = tid & 63;
  const int w    = tid >> 6;
  const int m    = w & 1;                   // m-tile (rows m*32..+32)
  const int p    = w >> 1;                  // K-half
  const int colW = l & 31;                  // C col / A row-in-tile
  const int khB  = l >> 5;                  // k-half within unit
  const bool validC = (colW < 24);
  const int colB = validC ? colW : colW - 24;
  const int gran = colB*2 + khB;
  const int grr  = gran >> 3, gcc = gran & 7;
  const int bfi  = grr*8 + (gcc ^ (grr & 7));   // f16x8 index within a 768B unit-block

  // per-(g,t) barrier counters: ctr[2048 + g*16384 + t*32]  [r6 verified]
  u32* FL = ctr + 2048 + (size_t)gx*16384;

  // stage packed weight slice global -> LDS (153.6 KB)
  {
    const float4* srcw = reinterpret_cast<const float4*>(Wb + (size_t)s*76800);
    float4* dst = reinterpret_cast<float4*>(smem);
    for (int i = tid; i < 9600; i += 256) dst[i] = srcw[i];
  }
  __syncthreads();

  const f16x8* WBp = reinterpret_cast<const f16x8*>(smem);
  float* scr = reinterpret_cast<float*>(smem + 76800);   // 8KB reduce scratch, e-major

  // x-unit B-frags (units 0..3, both mats) held permanently in registers (p==0)
  f16x8 xbh[4], xbp[4];
  if (p == 0){
#pragma unroll
    for (int u = 0; u < 4; ++u){ xbh[u] = WBp[u*48 + bfi]; xbp[u] = WBp[(100+u)*48 + bfi]; }
  }

  const int dcol = c0 + (validC ? colW : 0);
  const float bhv = bh_g[dcol];
  const float bpv = bp_g[dcol];

  float hz[16] = {}, hy[16] = {};           // fp32 master state (p==0 waves)

  auto wait_cnt = [&](const u32* cp){
    if (s_dead) return;
    long spins = 0;
    while (__hip_atomic_load(cp, __ATOMIC_RELAXED, __HIP_MEMORY_SCOPE_AGENT) < 32u){
      __builtin_amdgcn_s_sleep(1);
      if (++spins > 1000000L){ if (l == 0) s_dead = 1; break; }
    }
  };

#define STATE_LOOP(U0c, NUc) do { \
    f16x8 av[4]; \
    _Pragma("unroll") \
    for (int i = 0; i < 4; ++i) av[i] = *reinterpret_cast<const f16x8*>(stb + (size_t)((U0c)-4+i)*16); \
    _Pragma("unroll") \
    for (int i = 0; i < (NUc); ++i){ \
      f16x8 a = av[i & 3]; \
      if (i + 4 < (NUc)) av[i & 3] = *reinterpret_cast<const f16x8*>(stb + (size_t)((U0c)+i)*16); \
      f16x8 bh8 = WBp[((U0c)+i)*48 + bfi]; \
      f16x8 bp8 = WBp[(100+(U0c)+i)*48 + bfi]; \
      f16x8 asq = a*a; \
      accH = MFMA32(a,   bh8, accH); \
      accP = MFMA32(asq, bp8, accP); \
    } } while (0)

#pragma unroll 1
  for (int t = 0; t < T_STEPS; ++t){
    f32x16 accH = {}, accP = {};

    // x contribution (units 0..3): independent of the tile — done pre-wait
    if (p == 0){
      const float* xb = x + ((size_t)t*BATCH + gx*64 + m*32 + colW)*64 + khB*8;
#pragma unroll
      for (int u = 0; u < 4; ++u){
        const float4 uu = *reinterpret_cast<const float4*>(xb + u*16);
        const float4 vv = *reinterpret_cast<const float4*>(xb + u*16 + 4);
        f16x8 xa8, xs8;
        xa8[0]=(_Float16)uu.x; xa8[1]=(_Float16)uu.y; xa8[2]=(_Float16)uu.z; xa8[3]=(_Float16)uu.w;
        xa8[4]=(_Float16)vv.x; xa8[5]=(_Float16)vv.y; xa8[6]=(_Float16)vv.z; xa8[7]=(_Float16)vv.w;
        xs8[0]=(_Float16)(uu.x*uu.x); xs8[1]=(_Float16)(uu.y*uu.y); xs8[2]=(_Float16)(uu.z*uu.z); xs8[3]=(_Float16)(uu.w*uu.w);
        xs8[4]=(_Float16)(vv.x*vv.x); xs8[5]=(_Float16)(vv.y*vv.y); xs8[6]=(_Float16)(vv.z*vv.z); xs8[7]=(_Float16)(vv.w*vv.w);
        accH = MFMA32(xa8, xbh[u], accH);
        accP = MFMA32(xs8, xbp[u], accP);
      }
    }

    if (w == 0){
      if (t > 0) wait_cnt(FL + (size_t)(t-1)*32);
      ACQUIRE_L1();
    }
    __syncthreads();
    if (s_dead) break;

    // state A-frags: lane reads 16B at row = m*32+colW, k-offset khB*8 (plain layout)
    const u16* stb = st + ((((size_t)(t&1)*8 + gx)*64) + m*32 + colW)*1536 + khB*8;
    if (p == 0) STATE_LOOP(4, 46); else STATE_LOOP(50, 50);

    // cross-wave K-half reduce via e-major scratch (stride-1 lanes: 2-way
    // bank alias only — conflict-free per measured model). w2->w0, w3->w1.
    if (p == 1){
#pragma unroll
      for (int e = 0; e < 16; ++e) scr[e*128 + m*64 + l] = accH[e];
    }
    __syncthreads();
    if (p == 0){
#pragma unroll
      for (int e = 0; e < 16; ++e) accH[e] += scr[e*128 + m*64 + l];
    }
    __syncthreads();
    if (p == 1){
#pragma unroll
      for (int e = 0; e < 16; ++e) scr[e*128 + m*64 + l] = accP[e];
    }
    __syncthreads();
    if (p == 0){
#pragma unroll
      for (int e = 0; e < 16; ++e) accP[e] += scr[e*128 + m*64 + l];
    }

    // update + store (waves 0/1 only; lane covers col=colW, 16 rows)
    if (p == 0){
      u16* wtb = st + (((size_t)((t+1)&1)*8 + gx)*64)*1536;
#pragma unroll
      for (int e = 0; e < 16; ++e){
        float hv = ftanh(accH[e] + bhv);
        float pv = ftanh(accP[e] + bpv);
        hz[e] += DTF * (hv + pv);
        hy[e] += DTF * hz[e];
        if (validC){
          int row = m*32 + (e & 3) + 8*(e >> 2) + 4*khB;
          wtb[(size_t)row*1536 + dcol]       = f2h(hz[e]);
          wtb[(size_t)row*1536 + 768 + dcol] = f2h(hy[e]);
        }
      }
      asm volatile("s_waitcnt vmcnt(0)" ::: "memory");   // stores visible in XCD L2
    }
    __syncthreads();
    if (tid == 0)
      __hip_atomic_fetch_add(FL + (size_t)t*32, 1u, __ATOMIC_RELAXED, __HIP_MEMORY_SCOPE_AGENT);
  }
#undef STATE_LOOP

  // final projection: out = hy @ W_r^T + b_r, slot-0 block (16x16x32 path)
  if (s == 0 && !s_dead){
    if (w == 0){ wait_cnt(FL + (size_t)(T_STEPS-1)*32); ACQUIRE_L1(); }
    __syncthreads();
    if (!s_dead){
      const int colL = l & 15, kq4 = l >> 4;
      const u16* hyb = st + (((size_t)gx*64) + w*16 + colL)*1536 + 768 + kq4*8;  // buf0
      const f16x8* Wr8 = reinterpret_cast<const f16x8*>(Wrb);
      f32x4 oc[4] = {};
#pragma unroll
      for (int kt = 0; kt < 24; ++kt){
        f16x8 a = *reinterpret_cast<const f16x8*>(hyb + (size_t)kt*32);
#pragma unroll
        for (int nt = 0; nt < 4; ++nt)
          oc[nt] = MFMA16(a, Wr8[(nt*24 + kt)*64 + l], oc[nt]);
      }
      const int rowC = w*16 + kq4*4;
#pragma unroll
      for (int nt = 0; nt < 4; ++nt){
        float bb = br_g[nt*16 + colL];
#pragma unroll
        for (int e = 0; e < 4; ++e)
          out[(size_t)(gx*64 + rowC + e)*64 + nt*16 + colL] = oc[nt][e] + bb;
      }
    }
  }
}

extern "C" void kernel_launch(void* const* d_in, const int* in_sizes, int n_in,
                              void* d_out, int out_size, void* d_ws, size_t ws_size,
                              hipStream_t stream) {
  const float* x  = (const float*)d_in[0];
  const float* Wh = (const float*)d_in[1];
  const float* bh = (const float*)d_in[2];
  const float* Wp = (const float*)d_in[3];
  const float* bp = (const float*)d_in[4];
  const float* Wr = (const float*)d_in[5];
  const float* br = (const float*)d_in[6];
  float* out = (float*)d_out;

  if (ws_size < (size_t)WS_NEED) return;    // loud failure: output stays zero
  char* ws = (char*)d_ws;

  u16* Wb  = (u16*)(ws + WB_OFF);
  u16* Wrb = (u16*)(ws + WRB_OFF);
  u16* st  = (u16*)(ws + ST_OFF);
  u32* ctr = (u32*)(ws + CTR_OFF);

  hipMemsetAsync(ws + CTR_OFF, 0, CTR_SZ, stream);   // slot + barrier counters
  hipMemsetAsync(ws + ST_OFF,  0, ST_SZ,  stream);   // zero initial state (t=0)

  prep_weights<<<6496, 64, 0, stream>>>(Wh, Wp, Wr, Wb, Wrb);

  (void)hipFuncSetAttribute(reinterpret_cast<const void*>(rnn_main),
                            hipFuncAttributeMaxDynamicSharedMemorySize, 161792);
  rnn_main<<<256, 256, 161792, stream>>>(x, bh, bp, br, Wb, Wrb, st, ctr, out);
}